// Round 1
// baseline (831.995 us; speedup 1.0000x reference)
//
#include <hip/hip_runtime.h>

#define NN 50000
#define NE 800000
#define NG 256

// ---------------- degree / normalization precompute ----------------

__global__ void k_deg_init(float* deg, int n) {
    int i = blockIdx.x * blockDim.x + threadIdx.x;
    if (i < n) deg[i] = 1.0f;  // self-loop weight
}

__global__ void k_deg_scatter(float* deg, const int* __restrict__ dst,
                              const float* __restrict__ w, int e) {
    int i = blockIdx.x * blockDim.x + threadIdx.x;
    if (i < e) atomicAdd(&deg[dst[i]], w[i]);
}

__global__ void k_dinv_selfc(const float* __restrict__ deg, float* dinv, float* selfc, int n) {
    int i = blockIdx.x * blockDim.x + threadIdx.x;
    if (i < n) {
        float r = rsqrtf(deg[i]);   // deg >= 1 always (self loop)
        dinv[i] = r;
        selfc[i] = r * r;
    }
}

__global__ void k_coef(const int* __restrict__ src, const int* __restrict__ dst,
                       const float* __restrict__ w, const float* __restrict__ dinv,
                       float* coef, int e) {
    int i = blockIdx.x * blockDim.x + threadIdx.x;
    if (i < e) coef[i] = dinv[src[i]] * w[i] * dinv[dst[i]];
}

// ---------------- aggregation: out[n] = selfc[n]*h[n] + sum_e coef*h[src] ----------------

template<int F>
__global__ void k_init_self(float* __restrict__ out, const float* __restrict__ h,
                            const float* __restrict__ selfc, int n) {
    int t = blockIdx.x * blockDim.x + threadIdx.x;
    if (t < n * F) {
        int i = t / F;
        out[t] = selfc[i] * h[t];
    }
}

template<int F>
__global__ void k_edge_scatter(float* __restrict__ out, const float* __restrict__ h,
                               const int* __restrict__ src, const int* __restrict__ dst,
                               const float* __restrict__ coef, int e) {
    long long t = (long long)blockIdx.x * blockDim.x + threadIdx.x;
    int ei = (int)(t / F);
    int f  = (int)(t % F);
    if (ei < e) {
        int s = src[ei], d = dst[ei];
        atomicAdd(&out[(long long)d * F + f], coef[ei] * h[(long long)s * F + f]);
    }
}

// ---------------- dense layer: out = [relu](h @ W + b) ----------------

template<int FIN, int FOUT, bool RELU, bool BIAS>
__global__ void k_gemm(const float* __restrict__ h, const float* __restrict__ W,
                       const float* __restrict__ b, float* __restrict__ out, int n) {
    const int R = 256 / FOUT;               // rows per block
    __shared__ float Wl[FIN * FOUT];
    __shared__ float bl[FOUT];
    for (int i = threadIdx.x; i < FIN * FOUT; i += 256) Wl[i] = W[i];
    if (threadIdx.x < FOUT) bl[threadIdx.x] = BIAS ? b[threadIdx.x] : 0.0f;
    __syncthreads();
    int r  = threadIdx.x / FOUT;
    int fo = threadIdx.x % FOUT;
    int row = blockIdx.x * R + r;
    if (row >= n) return;
    const float* hr = h + (long long)row * FIN;
    float acc = bl[fo];
    #pragma unroll
    for (int fi = 0; fi < FIN; ++fi) acc += hr[fi] * Wl[fi * FOUT + fo];
    if (RELU) acc = fmaxf(acc, 0.0f);
    out[(long long)row * FOUT + fo] = acc;
}

// bias + relu applied in place (layer 1, aggregate-after-transform path)
template<int F, bool RELU>
__global__ void k_bias_relu(float* __restrict__ out, const float* __restrict__ b, int n) {
    int t = blockIdx.x * blockDim.x + threadIdx.x;
    if (t < n * F) {
        float v = out[t] + b[t % F];
        out[t] = RELU ? fmaxf(v, 0.0f) : v;
    }
}

// ---------------- global add pool + relu (batch is sorted) ----------------

__global__ void k_pool(const float* __restrict__ h, const int* __restrict__ batch,
                       float* __restrict__ out, int n) {
    int g = blockIdx.x;                      // one block per graph, 128 threads
    int lo = 0, hi = n;
    while (lo < hi) { int m = (lo + hi) >> 1; if (batch[m] < g) lo = m + 1; else hi = m; }
    int start = lo;
    hi = n;
    while (lo < hi) { int m = (lo + hi) >> 1; if (batch[m] < g + 1) lo = m + 1; else hi = m; }
    int end = lo;
    int f = threadIdx.x;
    float acc = 0.0f;
    for (int i = start; i < end; ++i) acc += h[(long long)i * 128 + f];
    out[g * 128 + f] = fmaxf(acc, 0.0f);
}

// ---------------- launch ----------------

static inline int cdiv(long long a, int b) { return (int)((a + b - 1) / b); }

extern "C" void kernel_launch(void* const* d_in, const int* in_sizes, int n_in,
                              void* d_out, int out_size, void* d_ws, size_t ws_size,
                              hipStream_t stream) {
    const float* x    = (const float*)d_in[0];
    const int*   src  = (const int*)d_in[1];
    const int*   dst  = src + NE;
    const float* ew   = (const float*)d_in[2];
    const int*   batch= (const int*)d_in[3];
    const float* W1 = (const float*)d_in[4];  const float* b1 = (const float*)d_in[5];
    const float* W2 = (const float*)d_in[6];  const float* b2 = (const float*)d_in[7];
    const float* W3 = (const float*)d_in[8];  const float* b3 = (const float*)d_in[9];
    const float* W4 = (const float*)d_in[10]; const float* b4 = (const float*)d_in[11];
    const float* W5 = (const float*)d_in[12]; const float* b5 = (const float*)d_in[13];
    float* out = (float*)d_out;

    float* ws    = (float*)d_ws;
    float* deg   = ws;                       // N
    float* dinv  = deg + NN;                 // N
    float* selfc = dinv + NN;                // N
    float* coef  = selfc + NN;               // E
    float* bufA  = coef + NE;                // N*64  (agg / xw buffer)
    float* bufB  = bufA + (size_t)NN * 64;   // N*128 (h buffer)

    const int T = 256;

    // normalization coefficients (shared across all 5 layers)
    k_deg_init<<<cdiv(NN, T), T, 0, stream>>>(deg, NN);
    k_deg_scatter<<<cdiv(NE, T), T, 0, stream>>>(deg, dst, ew, NE);
    k_dinv_selfc<<<cdiv(NN, T), T, 0, stream>>>(deg, dinv, selfc, NN);
    k_coef<<<cdiv(NE, T), T, 0, stream>>>(src, dst, ew, dinv, coef, NE);

    // ---- layer 1: 64 -> 16 (transform first: Fout < Fin) ----
    k_gemm<64, 16, false, false><<<cdiv(NN, 16), T, 0, stream>>>(x, W1, nullptr, bufA, NN);
    k_init_self<16><<<cdiv((long long)NN * 16, T), T, 0, stream>>>(bufB, bufA, selfc, NN);
    k_edge_scatter<16><<<cdiv((long long)NE * 16, T), T, 0, stream>>>(bufB, bufA, src, dst, coef, NE);
    k_bias_relu<16, true><<<cdiv((long long)NN * 16, T), T, 0, stream>>>(bufB, b1, NN);

    // ---- layer 2: 16 -> 32 (aggregate first: Fin <= Fout) ----
    k_init_self<16><<<cdiv((long long)NN * 16, T), T, 0, stream>>>(bufA, bufB, selfc, NN);
    k_edge_scatter<16><<<cdiv((long long)NE * 16, T), T, 0, stream>>>(bufA, bufB, src, dst, coef, NE);
    k_gemm<16, 32, true, true><<<cdiv(NN, 8), T, 0, stream>>>(bufA, W2, b2, bufB, NN);

    // ---- layer 3: 32 -> 64 ----
    k_init_self<32><<<cdiv((long long)NN * 32, T), T, 0, stream>>>(bufA, bufB, selfc, NN);
    k_edge_scatter<32><<<cdiv((long long)NE * 32, T), T, 0, stream>>>(bufA, bufB, src, dst, coef, NE);
    k_gemm<32, 64, true, true><<<cdiv(NN, 4), T, 0, stream>>>(bufA, W3, b3, bufB, NN);

    // ---- layer 4: 64 -> 64 ----
    k_init_self<64><<<cdiv((long long)NN * 64, T), T, 0, stream>>>(bufA, bufB, selfc, NN);
    k_edge_scatter<64><<<cdiv((long long)NE * 64, T), T, 0, stream>>>(bufA, bufB, src, dst, coef, NE);
    k_gemm<64, 64, true, true><<<cdiv(NN, 4), T, 0, stream>>>(bufA, W4, b4, bufB, NN);

    // ---- layer 5: 64 -> 128 ----
    k_init_self<64><<<cdiv((long long)NN * 64, T), T, 0, stream>>>(bufA, bufB, selfc, NN);
    k_edge_scatter<64><<<cdiv((long long)NE * 64, T), T, 0, stream>>>(bufA, bufB, src, dst, coef, NE);
    k_gemm<64, 128, false, true><<<cdiv(NN, 2), T, 0, stream>>>(bufA, W5, b5, bufB, NN);

    // ---- global add pool + relu ----
    k_pool<<<NG, 128, 0, stream>>>(bufB, batch, out, NN);
}

// Round 2
// 506.594 us; speedup vs baseline: 1.6423x; 1.6423x over previous
//
#include <hip/hip_runtime.h>

#define NN 50000
#define NE 800000
#define NG 256

// ================= CSR build + normalization =================

__global__ void k_init(float* deg, int* cnt, int n) {
    int i = blockIdx.x * blockDim.x + threadIdx.x;
    if (i < n) { deg[i] = 1.0f; cnt[i] = 0; }   // self-loop weight 1
}

__global__ void k_hist(float* deg, int* cnt, const int* __restrict__ dst,
                       const float* __restrict__ w, int e) {
    int i = blockIdx.x * blockDim.x + threadIdx.x;
    if (i < e) {
        int d = dst[i];
        atomicAdd(&deg[d], w[i]);
        atomicAdd(&cnt[d], 1);
    }
}

__global__ void k_dinv(const float* __restrict__ deg, float* dinv, float* selfc,
                       int* cursor, int n) {
    int i = blockIdx.x * blockDim.x + threadIdx.x;
    if (i < n) {
        float r = rsqrtf(deg[i]);   // deg >= 1 (self loop)
        dinv[i] = r;
        selfc[i] = r * r;
        cursor[i] = 0;
    }
}

// block-wise exclusive scan of cnt -> rowptr (1024/block)
__global__ void k_scan1(const int* __restrict__ cnt, int* rowptr, int* bsum, int n) {
    __shared__ int sm[1024];
    int t = threadIdx.x;
    int i = blockIdx.x * 1024 + t;
    int v = (i < n) ? cnt[i] : 0;
    sm[t] = v;
    __syncthreads();
    for (int off = 1; off < 1024; off *= 2) {
        int u = (t >= off) ? sm[t - off] : 0;
        __syncthreads();
        sm[t] += u;
        __syncthreads();
    }
    if (i < n) rowptr[i] = sm[t] - v;           // exclusive within block
    if (t == 1023) bsum[blockIdx.x] = sm[1023];
}

__global__ void k_scan2(const int* __restrict__ bsum, int* boff, int nb) {
    int l = threadIdx.x;                         // 64 lanes
    int v = (l < nb) ? bsum[l] : 0;
    int inc = v;
    for (int off = 1; off < 64; off *= 2) {
        int u = __shfl_up(inc, off);
        if (l >= off) inc += u;
    }
    if (l < nb) boff[l] = inc - v;
}

__global__ void k_scan3(int* rowptr, const int* __restrict__ boff, int n, int e) {
    int i = blockIdx.x * 1024 + threadIdx.x;
    if (i < n) rowptr[i] += boff[blockIdx.x];
    if (i == 0) rowptr[n] = e;
}

// scatter edges into CSR order; store (src, coef) packed
__global__ void k_fill(const int* __restrict__ src, const int* __restrict__ dst,
                       const float* __restrict__ w, const float* __restrict__ dinv,
                       const int* __restrict__ rowptr, int* cursor,
                       int2* sedge, int e) {
    int i = blockIdx.x * blockDim.x + threadIdx.x;
    if (i < e) {
        int s = src[i], d = dst[i];
        int p = rowptr[d] + atomicAdd(&cursor[d], 1);
        float c = dinv[s] * w[i] * dinv[d];
        sedge[p] = make_int2(s, __float_as_int(c));
    }
}

// ====== aggregation (gather): out[n] = selfc[n]*h[n] + sum coef*h[src] ======

template<int F, bool BRELU>
__global__ void k_agg(const float* __restrict__ h, const int* __restrict__ rowptr,
                      const int2* __restrict__ se, const float* __restrict__ selfc,
                      const float* __restrict__ bias, float* __restrict__ out, int n) {
    constexpr int G = F / 4;                     // lanes per node (float4 each)
    constexpr int NPB = 256 / G;
    int gid = blockIdx.x * NPB + threadIdx.x / G;
    int lane = threadIdx.x & (G - 1);
    if (gid >= n) return;
    const float4* h4 = (const float4*)h;
    float sc = selfc[gid];
    float4 a = h4[(long long)gid * G + lane];
    float4 acc = make_float4(a.x * sc, a.y * sc, a.z * sc, a.w * sc);
    int e0 = rowptr[gid], e1 = rowptr[gid + 1];
    for (int p = e0; p < e1; ++p) {
        int2 ed = se[p];
        float c = __int_as_float(ed.y);
        float4 hv = h4[(long long)ed.x * G + lane];
        acc.x += c * hv.x; acc.y += c * hv.y; acc.z += c * hv.z; acc.w += c * hv.w;
    }
    if (BRELU) {
        float4 bv = ((const float4*)bias)[lane];
        acc.x = fmaxf(acc.x + bv.x, 0.0f); acc.y = fmaxf(acc.y + bv.y, 0.0f);
        acc.z = fmaxf(acc.z + bv.z, 0.0f); acc.w = fmaxf(acc.w + bv.w, 0.0f);
    }
    ((float4*)out)[(long long)gid * G + lane] = acc;
}

// ================= dense layer: out = [relu](h @ W + b) =================

template<int FIN, int FOUT, bool RELU, bool BIAS>
__global__ void k_gemm(const float* __restrict__ h, const float* __restrict__ W,
                       const float* __restrict__ b, float* __restrict__ out, int n) {
    const int R = 256 / FOUT;                    // rows per block
    __shared__ float Wl[FIN * FOUT];
    __shared__ float bl[FOUT];
    for (int i = threadIdx.x; i < FIN * FOUT; i += 256) Wl[i] = W[i];
    if (threadIdx.x < FOUT) bl[threadIdx.x] = BIAS ? b[threadIdx.x] : 0.0f;
    __syncthreads();
    int r  = threadIdx.x / FOUT;
    int fo = threadIdx.x % FOUT;
    int row = blockIdx.x * R + r;
    if (row >= n) return;
    const float* hr = h + (long long)row * FIN;
    float acc = bl[fo];
    #pragma unroll
    for (int fi = 0; fi < FIN; ++fi) acc += hr[fi] * Wl[fi * FOUT + fo];
    if (RELU) acc = fmaxf(acc, 0.0f);
    out[(long long)row * FOUT + fo] = acc;
}

// ================= global add pool + relu (batch sorted) =================

__global__ void k_pool(const float* __restrict__ h, const int* __restrict__ batch,
                       float* __restrict__ out, int n) {
    int g = blockIdx.x;                          // one block per graph, 128 threads
    int lo = 0, hi = n;
    while (lo < hi) { int m = (lo + hi) >> 1; if (batch[m] < g) lo = m + 1; else hi = m; }
    int start = lo;
    hi = n;
    while (lo < hi) { int m = (lo + hi) >> 1; if (batch[m] < g + 1) lo = m + 1; else hi = m; }
    int end = lo;
    int f = threadIdx.x;
    float acc = 0.0f;
    for (int i = start; i < end; ++i) acc += h[(long long)i * 128 + f];
    out[g * 128 + f] = fmaxf(acc, 0.0f);
}

// ================= launch =================

static inline int cdiv(long long a, int b) { return (int)((a + b - 1) / b); }

extern "C" void kernel_launch(void* const* d_in, const int* in_sizes, int n_in,
                              void* d_out, int out_size, void* d_ws, size_t ws_size,
                              hipStream_t stream) {
    const float* x    = (const float*)d_in[0];
    const int*   src  = (const int*)d_in[1];
    const int*   dst  = src + NE;
    const float* ew   = (const float*)d_in[2];
    const int*   batch= (const int*)d_in[3];
    const float* W1 = (const float*)d_in[4];  const float* b1 = (const float*)d_in[5];
    const float* W2 = (const float*)d_in[6];  const float* b2 = (const float*)d_in[7];
    const float* W3 = (const float*)d_in[8];  const float* b3 = (const float*)d_in[9];
    const float* W4 = (const float*)d_in[10]; const float* b4 = (const float*)d_in[11];
    const float* W5 = (const float*)d_in[12]; const float* b5 = (const float*)d_in[13];
    float* out = (float*)d_out;

    // ---- workspace layout (all regions padded to 16B alignment) ----
    float* ws = (float*)d_ws;
    int*   rowptr = (int*)ws;                         // N+1 ints (pad to 50004)
    int2*  sedge  = (int2*)(ws + 50004);              // E int2 (2E floats)
    float* selfc  = ws + 50004 + 2 * (size_t)NE;      // N floats
    float* bufA   = selfc + NN;                       // N*64
    float* bufB   = bufA + (size_t)NN * 64;           // N*128
    // CSR-build temporaries live inside bufA (dead before first layer writes it)
    float* deg    = bufA;                             // N
    float* dinv   = bufA + NN;                        // N
    int*   cnt    = (int*)(bufA + 2 * (size_t)NN);    // N
    int*   cursor = (int*)(bufA + 3 * (size_t)NN);    // N
    int*   bsum   = (int*)(bufA + 4 * (size_t)NN);    // 64
    int*   boff   = bsum + 64;                        // 64

    const int T = 256;
    const int NB = cdiv(NN, 1024);

    // ---- CSR + normalization (shared across all 5 layers) ----
    k_init<<<cdiv(NN, T), T, 0, stream>>>(deg, cnt, NN);
    k_hist<<<cdiv(NE, T), T, 0, stream>>>(deg, cnt, dst, ew, NE);
    k_dinv<<<cdiv(NN, T), T, 0, stream>>>(deg, dinv, selfc, cursor, NN);
    k_scan1<<<NB, 1024, 0, stream>>>(cnt, rowptr, bsum, NN);
    k_scan2<<<1, 64, 0, stream>>>(bsum, boff, NB);
    k_scan3<<<NB, 1024, 0, stream>>>(rowptr, boff, NN, NE);
    k_fill<<<cdiv(NE, T), T, 0, stream>>>(src, dst, ew, dinv, rowptr, cursor, sedge, NE);

    // ---- layer 1: 64 -> 16 (transform first since Fout < Fin) ----
    k_gemm<64, 16, false, false><<<cdiv(NN, 16), T, 0, stream>>>(x, W1, nullptr, bufA, NN);
    k_agg<16, true><<<cdiv(NN, 64), T, 0, stream>>>(bufA, rowptr, sedge, selfc, b1, bufB, NN);

    // ---- layer 2: 16 -> 32 (aggregate first) ----
    k_agg<16, false><<<cdiv(NN, 64), T, 0, stream>>>(bufB, rowptr, sedge, selfc, nullptr, bufA, NN);
    k_gemm<16, 32, true, true><<<cdiv(NN, 8), T, 0, stream>>>(bufA, W2, b2, bufB, NN);

    // ---- layer 3: 32 -> 64 ----
    k_agg<32, false><<<cdiv(NN, 32), T, 0, stream>>>(bufB, rowptr, sedge, selfc, nullptr, bufA, NN);
    k_gemm<32, 64, true, true><<<cdiv(NN, 4), T, 0, stream>>>(bufA, W3, b3, bufB, NN);

    // ---- layer 4: 64 -> 64 ----
    k_agg<64, false><<<cdiv(NN, 16), T, 0, stream>>>(bufB, rowptr, sedge, selfc, nullptr, bufA, NN);
    k_gemm<64, 64, true, true><<<cdiv(NN, 4), T, 0, stream>>>(bufA, W4, b4, bufB, NN);

    // ---- layer 5: 64 -> 128 ----
    k_agg<64, false><<<cdiv(NN, 16), T, 0, stream>>>(bufB, rowptr, sedge, selfc, nullptr, bufA, NN);
    k_gemm<64, 128, false, true><<<cdiv(NN, 2), T, 0, stream>>>(bufA, W5, b5, bufB, NN);

    // ---- global add pool + relu ----
    k_pool<<<NG, 128, 0, stream>>>(bufB, batch, out, NN);
}

// Round 3
// 398.944 us; speedup vs baseline: 2.0855x; 1.2698x over previous
//
#include <hip/hip_runtime.h>

#define NN 50000
#define NE 800000
#define NG 256

// ================= CSR build + normalization =================

__global__ void k_init(float* deg, int* cnt, int n) {
    int i = blockIdx.x * blockDim.x + threadIdx.x;
    if (i < n) { deg[i] = 1.0f; cnt[i] = 0; }   // self-loop weight 1
}

__global__ void k_hist(float* deg, int* cnt, const int* __restrict__ dst,
                       const float* __restrict__ w, int e) {
    int i = blockIdx.x * blockDim.x + threadIdx.x;
    if (i < e) {
        int d = dst[i];
        atomicAdd(&deg[d], w[i]);
        atomicAdd(&cnt[d], 1);
    }
}

__global__ void k_dinv(const float* __restrict__ deg, float* dinv, float* selfc,
                       int* cursor, int n) {
    int i = blockIdx.x * blockDim.x + threadIdx.x;
    if (i < n) {
        float r = rsqrtf(deg[i]);   // deg >= 1 (self loop)
        dinv[i] = r;
        selfc[i] = r * r;
        cursor[i] = 0;
    }
}

// block-wise exclusive scan of cnt -> rowptr (1024/block)
__global__ void k_scan1(const int* __restrict__ cnt, int* rowptr, int* bsum, int n) {
    __shared__ int sm[1024];
    int t = threadIdx.x;
    int i = blockIdx.x * 1024 + t;
    int v = (i < n) ? cnt[i] : 0;
    sm[t] = v;
    __syncthreads();
    for (int off = 1; off < 1024; off *= 2) {
        int u = (t >= off) ? sm[t - off] : 0;
        __syncthreads();
        sm[t] += u;
        __syncthreads();
    }
    if (i < n) rowptr[i] = sm[t] - v;           // exclusive within block
    if (t == 1023) bsum[blockIdx.x] = sm[1023];
}

__global__ void k_scan2(const int* __restrict__ bsum, int* boff, int nb) {
    int l = threadIdx.x;                         // 64 lanes
    int v = (l < nb) ? bsum[l] : 0;
    int inc = v;
    for (int off = 1; off < 64; off *= 2) {
        int u = __shfl_up(inc, off);
        if (l >= off) inc += u;
    }
    if (l < nb) boff[l] = inc - v;
}

__global__ void k_scan3(int* rowptr, const int* __restrict__ boff, int n, int e) {
    int i = blockIdx.x * 1024 + threadIdx.x;
    if (i < n) rowptr[i] += boff[blockIdx.x];
    if (i == 0) rowptr[n] = e;
}

// scatter edges into CSR order; store (src, coef) packed
__global__ void k_fill(const int* __restrict__ src, const int* __restrict__ dst,
                       const float* __restrict__ w, const float* __restrict__ dinv,
                       const int* __restrict__ rowptr, int* cursor,
                       int2* sedge, int e) {
    int i = blockIdx.x * blockDim.x + threadIdx.x;
    if (i < e) {
        int s = src[i], d = dst[i];
        int p = rowptr[d] + atomicAdd(&cursor[d], 1);
        float c = dinv[s] * w[i] * dinv[d];
        sedge[p] = make_int2(s, __float_as_int(c));
    }
}

// ====== aggregation (gather): out[n] = selfc[n]*h[n] + sum coef*h[src] ======

template<int F, bool BRELU>
__global__ void k_agg(const float* __restrict__ h, const int* __restrict__ rowptr,
                      const int2* __restrict__ se, const float* __restrict__ selfc,
                      const float* __restrict__ bias, float* __restrict__ out, int n) {
    constexpr int G = F / 4;                     // lanes per node (float4 each)
    constexpr int NPB = 256 / G;
    int gid = blockIdx.x * NPB + threadIdx.x / G;
    int lane = threadIdx.x & (G - 1);
    if (gid >= n) return;
    const float4* h4 = (const float4*)h;
    float sc = selfc[gid];
    float4 a = h4[(long long)gid * G + lane];
    float4 acc = make_float4(a.x * sc, a.y * sc, a.z * sc, a.w * sc);
    int e0 = rowptr[gid], e1 = rowptr[gid + 1];
    for (int p = e0; p < e1; ++p) {
        int2 ed = se[p];
        float c = __int_as_float(ed.y);
        float4 hv = h4[(long long)ed.x * G + lane];
        acc.x += c * hv.x; acc.y += c * hv.y; acc.z += c * hv.z; acc.w += c * hv.w;
    }
    if (BRELU) {
        float4 bv = ((const float4*)bias)[lane];
        acc.x = fmaxf(acc.x + bv.x, 0.0f); acc.y = fmaxf(acc.y + bv.y, 0.0f);
        acc.z = fmaxf(acc.z + bv.z, 0.0f); acc.w = fmaxf(acc.w + bv.w, 0.0f);
    }
    ((float4*)out)[(long long)gid * G + lane] = acc;
}

// ================= dense layer: out = [relu](h @ W + b) =================
// Register-tiled: block computes 64 x FOUT; thread computes R rows x 4 cols.
// h-tile staged TRANSPOSED in LDS (4x4 register transpose) so k-loop A-reads
// are contiguous ds_read_b128. W staged as float4 rows.

template<int FIN, int FOUT, bool RELU, bool BIAS>
__global__ __launch_bounds__(256) void k_gemm(const float* __restrict__ h,
                                              const float* __restrict__ W,
                                              const float* __restrict__ b,
                                              float* __restrict__ out, int n) {
    constexpr int TC = FOUT / 4;     // thread-cols (float4 each)
    constexpr int TR = 256 / TC;     // thread-rows
    constexpr int R  = 64 / TR;      // rows per thread
    constexpr int SA = 68;           // hT row stride (floats), 16B-aligned, bank-spread
    constexpr int CB = FIN / 4;      // 4-col blocks in h

    __shared__ float  hT[FIN * SA];
    __shared__ float4 Wl[FIN * TC];
    __shared__ float4 bl[TC];

    int tid = threadIdx.x;
    int rowbase = blockIdx.x * 64;

    // stage W (flat float4 copy)
    for (int i = tid; i < FIN * TC; i += 256) Wl[i] = ((const float4*)W)[i];
    if (BIAS && tid < TC) bl[tid] = ((const float4*)b)[tid];

    // stage h-tile transposed via 4x4 register transpose
    for (int blk = tid; blk < 16 * CB; blk += 256) {
        int br = blk / CB, bc = blk % CB;
        float4 v[4];
        #pragma unroll
        for (int i = 0; i < 4; ++i) {
            int rr = rowbase + 4 * br + i;
            if (rr >= n) rr = n - 1;            // clamp (stores are guarded)
            v[i] = *(const float4*)(h + (long long)rr * FIN + 4 * bc);
        }
        #pragma unroll
        for (int j = 0; j < 4; ++j) {
            float4 t;
            t.x = ((float*)&v[0])[j];
            t.y = ((float*)&v[1])[j];
            t.z = ((float*)&v[2])[j];
            t.w = ((float*)&v[3])[j];
            *(float4*)&hT[(4 * bc + j) * SA + 4 * br] = t;
        }
    }
    __syncthreads();

    int tc = tid % TC;
    int r0 = (tid / TC) * R;

    float4 acc[R];
    float4 binit = BIAS ? bl[tc] : make_float4(0.f, 0.f, 0.f, 0.f);
    #pragma unroll
    for (int r = 0; r < R; ++r) acc[r] = binit;

    #pragma unroll 4
    for (int fi = 0; fi < FIN; ++fi) {
        float4 wv = Wl[fi * TC + tc];
        float a[R];
        if constexpr (R >= 4) {
            #pragma unroll
            for (int rb = 0; rb < R / 4; ++rb) {
                float4 t = *(const float4*)&hT[fi * SA + r0 + 4 * rb];
                a[4 * rb + 0] = t.x; a[4 * rb + 1] = t.y;
                a[4 * rb + 2] = t.z; a[4 * rb + 3] = t.w;
            }
        } else if constexpr (R == 2) {
            float2 t = *(const float2*)&hT[fi * SA + r0];
            a[0] = t.x; a[1] = t.y;
        } else {
            a[0] = hT[fi * SA + r0];
        }
        #pragma unroll
        for (int r = 0; r < R; ++r) {
            acc[r].x += a[r] * wv.x; acc[r].y += a[r] * wv.y;
            acc[r].z += a[r] * wv.z; acc[r].w += a[r] * wv.w;
        }
    }

    #pragma unroll
    for (int r = 0; r < R; ++r) {
        int row = rowbase + r0 + r;
        if (row < n) {
            float4 v = acc[r];
            if (RELU) {
                v.x = fmaxf(v.x, 0.f); v.y = fmaxf(v.y, 0.f);
                v.z = fmaxf(v.z, 0.f); v.w = fmaxf(v.w, 0.f);
            }
            *(float4*)(out + (long long)row * FOUT + 4 * tc) = v;
        }
    }
}

// ================= global add pool + relu (batch sorted) =================

__global__ void k_pool(const float* __restrict__ h, const int* __restrict__ batch,
                       float* __restrict__ out, int n) {
    int g = blockIdx.x;                          // one block per graph, 128 threads
    int lo = 0, hi = n;
    while (lo < hi) { int m = (lo + hi) >> 1; if (batch[m] < g) lo = m + 1; else hi = m; }
    int start = lo;
    hi = n;
    while (lo < hi) { int m = (lo + hi) >> 1; if (batch[m] < g + 1) lo = m + 1; else hi = m; }
    int end = lo;
    int f = threadIdx.x;
    float acc = 0.0f;
    for (int i = start; i < end; ++i) acc += h[(long long)i * 128 + f];
    out[g * 128 + f] = fmaxf(acc, 0.0f);
}

// ================= launch =================

static inline int cdiv(long long a, int b) { return (int)((a + b - 1) / b); }

extern "C" void kernel_launch(void* const* d_in, const int* in_sizes, int n_in,
                              void* d_out, int out_size, void* d_ws, size_t ws_size,
                              hipStream_t stream) {
    const float* x    = (const float*)d_in[0];
    const int*   src  = (const int*)d_in[1];
    const int*   dst  = src + NE;
    const float* ew   = (const float*)d_in[2];
    const int*   batch= (const int*)d_in[3];
    const float* W1 = (const float*)d_in[4];  const float* b1 = (const float*)d_in[5];
    const float* W2 = (const float*)d_in[6];  const float* b2 = (const float*)d_in[7];
    const float* W3 = (const float*)d_in[8];  const float* b3 = (const float*)d_in[9];
    const float* W4 = (const float*)d_in[10]; const float* b4 = (const float*)d_in[11];
    const float* W5 = (const float*)d_in[12]; const float* b5 = (const float*)d_in[13];
    float* out = (float*)d_out;

    // ---- workspace layout ----
    float* ws = (float*)d_ws;
    int*   rowptr = (int*)ws;                         // N+1 ints (pad to 50004)
    int2*  sedge  = (int2*)(ws + 50004);              // E int2
    float* selfc  = ws + 50004 + 2 * (size_t)NE;      // N floats
    float* bufA   = selfc + NN;                       // N*64
    float* bufB   = bufA + (size_t)NN * 64;           // N*128
    // CSR-build temporaries live inside bufA (dead before first layer writes it)
    float* deg    = bufA;                             // N
    float* dinv   = bufA + NN;                        // N
    int*   cnt    = (int*)(bufA + 2 * (size_t)NN);    // N
    int*   cursor = (int*)(bufA + 3 * (size_t)NN);    // N
    int*   bsum   = (int*)(bufA + 4 * (size_t)NN);    // 64
    int*   boff   = bsum + 64;                        // 64

    const int T = 256;
    const int NB = cdiv(NN, 1024);

    // ---- CSR + normalization (shared across all 5 layers) ----
    k_init<<<cdiv(NN, T), T, 0, stream>>>(deg, cnt, NN);
    k_hist<<<cdiv(NE, T), T, 0, stream>>>(deg, cnt, dst, ew, NE);
    k_dinv<<<cdiv(NN, T), T, 0, stream>>>(deg, dinv, selfc, cursor, NN);
    k_scan1<<<NB, 1024, 0, stream>>>(cnt, rowptr, bsum, NN);
    k_scan2<<<1, 64, 0, stream>>>(bsum, boff, NB);
    k_scan3<<<NB, 1024, 0, stream>>>(rowptr, boff, NN, NE);
    k_fill<<<cdiv(NE, T), T, 0, stream>>>(src, dst, ew, dinv, rowptr, cursor, sedge, NE);

    // ---- layer 1: 64 -> 16 (transform first since Fout < Fin) ----
    k_gemm<64, 16, false, false><<<cdiv(NN, 64), T, 0, stream>>>(x, W1, nullptr, bufA, NN);
    k_agg<16, true><<<cdiv(NN, 64), T, 0, stream>>>(bufA, rowptr, sedge, selfc, b1, bufB, NN);

    // ---- layer 2: 16 -> 32 (aggregate first) ----
    k_agg<16, false><<<cdiv(NN, 64), T, 0, stream>>>(bufB, rowptr, sedge, selfc, nullptr, bufA, NN);
    k_gemm<16, 32, true, true><<<cdiv(NN, 64), T, 0, stream>>>(bufA, W2, b2, bufB, NN);

    // ---- layer 3: 32 -> 64 ----
    k_agg<32, false><<<cdiv(NN, 32), T, 0, stream>>>(bufB, rowptr, sedge, selfc, nullptr, bufA, NN);
    k_gemm<32, 64, true, true><<<cdiv(NN, 64), T, 0, stream>>>(bufA, W3, b3, bufB, NN);

    // ---- layer 4: 64 -> 64 ----
    k_agg<64, false><<<cdiv(NN, 16), T, 0, stream>>>(bufB, rowptr, sedge, selfc, nullptr, bufA, NN);
    k_gemm<64, 64, true, true><<<cdiv(NN, 64), T, 0, stream>>>(bufA, W4, b4, bufB, NN);

    // ---- layer 5: 64 -> 128 ----
    k_agg<64, false><<<cdiv(NN, 16), T, 0, stream>>>(bufB, rowptr, sedge, selfc, nullptr, bufA, NN);
    k_gemm<64, 128, false, true><<<cdiv(NN, 64), T, 0, stream>>>(bufA, W5, b5, bufB, NN);

    // ---- global add pool + relu ----
    k_pool<<<NG, 128, 0, stream>>>(bufB, batch, out, NN);
}

// Round 4
// 333.322 us; speedup vs baseline: 2.4961x; 1.1969x over previous
//
#include <hip/hip_runtime.h>

#define NN 50000
#define NE 800000
#define NG 256
#define NBUK 782            // ceil(NN/64)
#define EPB 4096            // edges per block in bucket passes
#define NBLK 196            // ceil(NE/EPB)

// ================= CSR build via two-level counting sort =================

__global__ void k_bzero(int* bucketCnt) {
    int i = blockIdx.x * blockDim.x + threadIdx.x;
    if (i <= NBUK) bucketCnt[i] = 0;
}

// pass A1: per-block LDS histogram over buckets, reserve ranges with one
// global atomic per (block,bucket)
__global__ __launch_bounds__(256) void kA1(const int* __restrict__ dst,
                                           int* __restrict__ bucketCnt,
                                           int* __restrict__ pbb) {
    __shared__ int hist[NBUK];
    for (int k = threadIdx.x; k < NBUK; k += 256) hist[k] = 0;
    __syncthreads();
    int b = blockIdx.x;
    int e0 = b * EPB, e1 = min(NE, e0 + EPB);
    for (int i = e0 + threadIdx.x; i < e1; i += 256)
        atomicAdd(&hist[dst[i] >> 6], 1);
    __syncthreads();
    for (int k = threadIdx.x; k < NBUK; k += 256) {
        int c = hist[k];
        if (c) pbb[k * NBLK + b] = atomicAdd(&bucketCnt[k], c);
    }
}

// exclusive scan of 782 bucket counts (single block)
__global__ __launch_bounds__(1024) void k_bscan(const int* __restrict__ bucketCnt,
                                                int* __restrict__ bucketBase,
                                                int* __restrict__ rowptr) {
    __shared__ int wsum[16];
    int tid = threadIdx.x;
    int v = (tid < NBUK) ? bucketCnt[tid] : 0;
    int inc = v;
    for (int off = 1; off < 64; off *= 2) {
        int u = __shfl_up(inc, off);
        if ((tid & 63) >= off) inc += u;
    }
    if ((tid & 63) == 63) wsum[tid >> 6] = inc;
    __syncthreads();
    if (tid < 16) {
        int w = wsum[tid], winc = w;
        for (int off = 1; off < 16; off *= 2) {
            int u = __shfl_up(winc, off);
            if (tid >= off) winc += u;
        }
        wsum[tid] = winc - w;          // exclusive wave offset
    }
    __syncthreads();
    int ex = inc - v + wsum[tid >> 6];
    if (tid <= NBUK) bucketBase[tid] = ex;   // tid==NBUK -> total == NE
    if (tid == 0) rowptr[NN] = NE;
}

// pass A2: recompute LDS histogram, scatter packed edges into bucket ranges
__global__ __launch_bounds__(256) void kA2(const int* __restrict__ src,
                                           const int* __restrict__ dst,
                                           const float* __restrict__ w,
                                           const int* __restrict__ bucketBase,
                                           const int* __restrict__ pbb,
                                           int2* __restrict__ tmp) {
    __shared__ int hist[NBUK];
    __shared__ int base[NBUK];
    for (int k = threadIdx.x; k < NBUK; k += 256) hist[k] = 0;
    __syncthreads();
    int b = blockIdx.x;
    int e0 = b * EPB, e1 = min(NE, e0 + EPB);
    for (int i = e0 + threadIdx.x; i < e1; i += 256)
        atomicAdd(&hist[dst[i] >> 6], 1);
    __syncthreads();
    for (int k = threadIdx.x; k < NBUK; k += 256) {
        if (hist[k]) base[k] = bucketBase[k] + pbb[k * NBLK + b];
        hist[k] = 0;                   // reuse as cursor
    }
    __syncthreads();
    for (int i = e0 + threadIdx.x; i < e1; i += 256) {
        int d = dst[i];
        int k = d >> 6;
        int pos = base[k] + atomicAdd(&hist[k], 1);
        tmp[pos] = make_int2(((d & 63) << 16) | src[i], __float_as_int(w[i]));
    }
}

// pass B: one block per bucket -> counting sort by dst&63, rowptr, deg/dinv/selfc
__global__ __launch_bounds__(256) void kB(const int2* __restrict__ tmp,
                                          const int* __restrict__ bucketBase,
                                          int* __restrict__ rowptr,
                                          float* __restrict__ dinv,
                                          float* __restrict__ selfc,
                                          int2* __restrict__ sedge) {
    __shared__ int   cnt[64];
    __shared__ float degs[64];
    __shared__ int   curs[64];
    int b = blockIdx.x;
    int tid = threadIdx.x;
    if (tid < 64) { cnt[tid] = 0; degs[tid] = 0.f; }
    __syncthreads();
    int s0 = bucketBase[b], s1 = bucketBase[b + 1];
    for (int p = s0 + tid; p < s1; p += 256) {
        int2 e = tmp[p];
        int n6 = e.x >> 16;
        atomicAdd(&cnt[n6], 1);
        atomicAdd(&degs[n6], __int_as_float(e.y));
    }
    __syncthreads();
    if (tid < 64) {
        int c = cnt[tid];
        int inc = c;
        for (int off = 1; off < 64; off *= 2) {
            int u = __shfl_up(inc, off);
            if (tid >= off) inc += u;
        }
        int ex = inc - c;
        curs[tid] = ex;
        int node = b * 64 + tid;
        if (node < NN) {
            rowptr[node] = s0 + ex;
            float deg = 1.0f + degs[tid];
            float r = rsqrtf(deg);
            dinv[node] = r;
            selfc[node] = r * r;
        }
    }
    __syncthreads();
    for (int p = s0 + tid; p < s1; p += 256) {
        int2 e = tmp[p];
        int n6 = e.x >> 16;
        int pos = s0 + atomicAdd(&curs[n6], 1);
        sedge[pos] = make_int2(e.x & 0xFFFF, e.y);   // (src, w bits)
    }
}

// convert stored w -> coef = dinv[src]*w*dinv[dst], in CSR order
__global__ void k_coef(const int* __restrict__ rowptr, const float* __restrict__ dinv,
                       int2* __restrict__ sedge) {
    int r = blockIdx.x * blockDim.x + threadIdx.x;
    if (r >= NN) return;
    int e0 = rowptr[r], e1 = rowptr[r + 1];
    float dr = dinv[r];
    for (int p = e0; p < e1; ++p) {
        int2 e = sedge[p];
        float c = dinv[e.x] * __int_as_float(e.y) * dr;
        sedge[p] = make_int2(e.x, __float_as_int(c));
    }
}

// ====== aggregation (gather): out[n] = selfc[n]*h[n] + sum coef*h[src] ======

template<int F, bool BRELU>
__global__ void k_agg(const float* __restrict__ h, const int* __restrict__ rowptr,
                      const int2* __restrict__ se, const float* __restrict__ selfc,
                      const float* __restrict__ bias, float* __restrict__ out, int n) {
    constexpr int G = F / 4;                     // lanes per node (float4 each)
    constexpr int NPB = 256 / G;
    int gid = blockIdx.x * NPB + threadIdx.x / G;
    int lane = threadIdx.x & (G - 1);
    if (gid >= n) return;
    const float4* h4 = (const float4*)h;
    float sc = selfc[gid];
    float4 a = h4[(long long)gid * G + lane];
    float4 acc = make_float4(a.x * sc, a.y * sc, a.z * sc, a.w * sc);
    int e0 = rowptr[gid], e1 = rowptr[gid + 1];
    for (int p = e0; p < e1; ++p) {
        int2 ed = se[p];
        float c = __int_as_float(ed.y);
        float4 hv = h4[(long long)ed.x * G + lane];
        acc.x += c * hv.x; acc.y += c * hv.y; acc.z += c * hv.z; acc.w += c * hv.w;
    }
    if (BRELU) {
        float4 bv = ((const float4*)bias)[lane];
        acc.x = fmaxf(acc.x + bv.x, 0.0f); acc.y = fmaxf(acc.y + bv.y, 0.0f);
        acc.z = fmaxf(acc.z + bv.z, 0.0f); acc.w = fmaxf(acc.w + bv.w, 0.0f);
    }
    ((float4*)out)[(long long)gid * G + lane] = acc;
}

// ================= dense layer: out = [relu](h @ W + b) =================

template<int FIN, int FOUT, bool RELU, bool BIAS>
__global__ __launch_bounds__(256) void k_gemm(const float* __restrict__ h,
                                              const float* __restrict__ W,
                                              const float* __restrict__ b,
                                              float* __restrict__ out, int n) {
    constexpr int TC = FOUT / 4;     // thread-cols (float4 each)
    constexpr int TR = 256 / TC;     // thread-rows
    constexpr int R  = 64 / TR;      // rows per thread
    constexpr int SA = 68;           // hT row stride (floats)
    constexpr int CB = FIN / 4;      // 4-col blocks in h

    __shared__ float  hT[FIN * SA];
    __shared__ float4 Wl[FIN * TC];
    __shared__ float4 bl[TC];

    int tid = threadIdx.x;
    int rowbase = blockIdx.x * 64;

    for (int i = tid; i < FIN * TC; i += 256) Wl[i] = ((const float4*)W)[i];
    if (BIAS && tid < TC) bl[tid] = ((const float4*)b)[tid];

    for (int blk = tid; blk < 16 * CB; blk += 256) {
        int br = blk / CB, bc = blk % CB;
        float4 v[4];
        #pragma unroll
        for (int i = 0; i < 4; ++i) {
            int rr = rowbase + 4 * br + i;
            if (rr >= n) rr = n - 1;
            v[i] = *(const float4*)(h + (long long)rr * FIN + 4 * bc);
        }
        #pragma unroll
        for (int j = 0; j < 4; ++j) {
            float4 t;
            t.x = ((float*)&v[0])[j];
            t.y = ((float*)&v[1])[j];
            t.z = ((float*)&v[2])[j];
            t.w = ((float*)&v[3])[j];
            *(float4*)&hT[(4 * bc + j) * SA + 4 * br] = t;
        }
    }
    __syncthreads();

    int tc = tid % TC;
    int r0 = (tid / TC) * R;

    float4 acc[R];
    float4 binit = BIAS ? bl[tc] : make_float4(0.f, 0.f, 0.f, 0.f);
    #pragma unroll
    for (int r = 0; r < R; ++r) acc[r] = binit;

    #pragma unroll 4
    for (int fi = 0; fi < FIN; ++fi) {
        float4 wv = Wl[fi * TC + tc];
        float a[R];
        if constexpr (R >= 4) {
            #pragma unroll
            for (int rb = 0; rb < R / 4; ++rb) {
                float4 t = *(const float4*)&hT[fi * SA + r0 + 4 * rb];
                a[4 * rb + 0] = t.x; a[4 * rb + 1] = t.y;
                a[4 * rb + 2] = t.z; a[4 * rb + 3] = t.w;
            }
        } else if constexpr (R == 2) {
            float2 t = *(const float2*)&hT[fi * SA + r0];
            a[0] = t.x; a[1] = t.y;
        } else {
            a[0] = hT[fi * SA + r0];
        }
        #pragma unroll
        for (int r = 0; r < R; ++r) {
            acc[r].x += a[r] * wv.x; acc[r].y += a[r] * wv.y;
            acc[r].z += a[r] * wv.z; acc[r].w += a[r] * wv.w;
        }
    }

    #pragma unroll
    for (int r = 0; r < R; ++r) {
        int row = rowbase + r0 + r;
        if (row < n) {
            float4 v = acc[r];
            if (RELU) {
                v.x = fmaxf(v.x, 0.f); v.y = fmaxf(v.y, 0.f);
                v.z = fmaxf(v.z, 0.f); v.w = fmaxf(v.w, 0.f);
            }
            *(float4*)(out + (long long)row * FOUT + 4 * tc) = v;
        }
    }
}

// ================= global add pool + relu (batch sorted) =================

__global__ void k_pool(const float* __restrict__ h, const int* __restrict__ batch,
                       float* __restrict__ out, int n) {
    int g = blockIdx.x;                          // one block per graph, 128 threads
    int lo = 0, hi = n;
    while (lo < hi) { int m = (lo + hi) >> 1; if (batch[m] < g) lo = m + 1; else hi = m; }
    int start = lo;
    hi = n;
    while (lo < hi) { int m = (lo + hi) >> 1; if (batch[m] < g + 1) lo = m + 1; else hi = m; }
    int end = lo;
    int f = threadIdx.x;
    float acc = 0.0f;
    for (int i = start; i < end; ++i) acc += h[(long long)i * 128 + f];
    out[g * 128 + f] = fmaxf(acc, 0.0f);
}

// ================= launch =================

static inline int cdiv(long long a, int b) { return (int)((a + b - 1) / b); }

extern "C" void kernel_launch(void* const* d_in, const int* in_sizes, int n_in,
                              void* d_out, int out_size, void* d_ws, size_t ws_size,
                              hipStream_t stream) {
    const float* x    = (const float*)d_in[0];
    const int*   src  = (const int*)d_in[1];
    const int*   dst  = src + NE;
    const float* ew   = (const float*)d_in[2];
    const int*   batch= (const int*)d_in[3];
    const float* W1 = (const float*)d_in[4];  const float* b1 = (const float*)d_in[5];
    const float* W2 = (const float*)d_in[6];  const float* b2 = (const float*)d_in[7];
    const float* W3 = (const float*)d_in[8];  const float* b3 = (const float*)d_in[9];
    const float* W4 = (const float*)d_in[10]; const float* b4 = (const float*)d_in[11];
    const float* W5 = (const float*)d_in[12]; const float* b5 = (const float*)d_in[13];
    float* out = (float*)d_out;

    // ---- workspace layout (floats) ----
    float* ws = (float*)d_ws;
    int*   rowptr = (int*)ws;                          // [50004] ints
    int2*  sedge  = (int2*)(ws + 50004);               // [NE] int2
    float* selfc  = ws + 50004 + 2 * (size_t)NE;       // [NN]
    float* dinv   = selfc + NN;                        // [NN]
    float* bufA   = dinv + NN;                         // [NN*64]
    float* bufB   = bufA + (size_t)NN * 64;            // [NN*128]
    // CSR-build scratch overlays dead regions:
    int*  pbb        = (int*)bufA;                     // NBUK*NBLK
    int*  bucketCnt  = pbb + NBUK * NBLK;              // NBUK+1
    int*  bucketBase = bucketCnt + NBUK + 1;           // NBUK+1
    int2* tmp        = (int2*)bufB;                    // NE

    const int T = 256;

    // ---- CSR build (shared across all 5 layers) ----
    k_bzero<<<cdiv(NBUK + 1, T), T, 0, stream>>>(bucketCnt);
    kA1<<<NBLK, T, 0, stream>>>(dst, bucketCnt, pbb);
    k_bscan<<<1, 1024, 0, stream>>>(bucketCnt, bucketBase, rowptr);
    kA2<<<NBLK, T, 0, stream>>>(src, dst, ew, bucketBase, pbb, tmp);
    kB<<<NBUK, T, 0, stream>>>(tmp, bucketBase, rowptr, dinv, selfc, sedge);
    k_coef<<<cdiv(NN, T), T, 0, stream>>>(rowptr, dinv, sedge);

    // ---- layer 1: 64 -> 16 (transform first since Fout < Fin) ----
    k_gemm<64, 16, false, false><<<cdiv(NN, 64), T, 0, stream>>>(x, W1, nullptr, bufA, NN);
    k_agg<16, true><<<cdiv(NN, 64), T, 0, stream>>>(bufA, rowptr, sedge, selfc, b1, bufB, NN);

    // ---- layer 2: 16 -> 32 (aggregate first) ----
    k_agg<16, false><<<cdiv(NN, 64), T, 0, stream>>>(bufB, rowptr, sedge, selfc, nullptr, bufA, NN);
    k_gemm<16, 32, true, true><<<cdiv(NN, 64), T, 0, stream>>>(bufA, W2, b2, bufB, NN);

    // ---- layer 3: 32 -> 64 ----
    k_agg<32, false><<<cdiv(NN, 32), T, 0, stream>>>(bufB, rowptr, sedge, selfc, nullptr, bufA, NN);
    k_gemm<32, 64, true, true><<<cdiv(NN, 64), T, 0, stream>>>(bufA, W3, b3, bufB, NN);

    // ---- layer 4: 64 -> 64 ----
    k_agg<64, false><<<cdiv(NN, 16), T, 0, stream>>>(bufB, rowptr, sedge, selfc, nullptr, bufA, NN);
    k_gemm<64, 64, true, true><<<cdiv(NN, 64), T, 0, stream>>>(bufA, W4, b4, bufB, NN);

    // ---- layer 5: 64 -> 128 ----
    k_agg<64, false><<<cdiv(NN, 16), T, 0, stream>>>(bufB, rowptr, sedge, selfc, nullptr, bufA, NN);
    k_gemm<64, 128, false, true><<<cdiv(NN, 64), T, 0, stream>>>(bufA, W5, b5, bufB, NN);

    // ---- global add pool + relu ----
    k_pool<<<NG, 128, 0, stream>>>(bufB, batch, out, NN);
}

// Round 5
// 262.575 us; speedup vs baseline: 3.1686x; 1.2694x over previous
//
#include <hip/hip_runtime.h>

#define NN 50000
#define NE 800000
#define NG 256
#define NBUK 782            // ceil(NN/64)
#define EPB 4096            // edges per block in bucket passes
#define NBLK 196            // ceil(NE/EPB)
#define PSLICE 8            // pool slices per graph

// ================= CSR build via two-level counting sort =================

__global__ void k_bzero(int* bucketCnt) {
    int i = blockIdx.x * blockDim.x + threadIdx.x;
    if (i <= NBUK) bucketCnt[i] = 0;
}

__global__ __launch_bounds__(256) void kA1(const int* __restrict__ dst,
                                           int* __restrict__ bucketCnt,
                                           int* __restrict__ pbb) {
    __shared__ int hist[NBUK];
    for (int k = threadIdx.x; k < NBUK; k += 256) hist[k] = 0;
    __syncthreads();
    int b = blockIdx.x;
    int e0 = b * EPB, e1 = min(NE, e0 + EPB);
    for (int i = e0 + threadIdx.x; i < e1; i += 256)
        atomicAdd(&hist[dst[i] >> 6], 1);
    __syncthreads();
    for (int k = threadIdx.x; k < NBUK; k += 256) {
        int c = hist[k];
        if (c) pbb[k * NBLK + b] = atomicAdd(&bucketCnt[k], c);
    }
}

__global__ __launch_bounds__(1024) void k_bscan(const int* __restrict__ bucketCnt,
                                                int* __restrict__ bucketBase,
                                                int* __restrict__ rowptr) {
    __shared__ int wsum[16];
    int tid = threadIdx.x;
    int v = (tid < NBUK) ? bucketCnt[tid] : 0;
    int inc = v;
    for (int off = 1; off < 64; off *= 2) {
        int u = __shfl_up(inc, off);
        if ((tid & 63) >= off) inc += u;
    }
    if ((tid & 63) == 63) wsum[tid >> 6] = inc;
    __syncthreads();
    if (tid < 16) {
        int w = wsum[tid], winc = w;
        for (int off = 1; off < 16; off *= 2) {
            int u = __shfl_up(winc, off);
            if (tid >= off) winc += u;
        }
        wsum[tid] = winc - w;
    }
    __syncthreads();
    int ex = inc - v + wsum[tid >> 6];
    if (tid <= NBUK) bucketBase[tid] = ex;
    if (tid == 0) rowptr[NN] = NE;
}

__global__ __launch_bounds__(256) void kA2(const int* __restrict__ src,
                                           const int* __restrict__ dst,
                                           const float* __restrict__ w,
                                           const int* __restrict__ bucketBase,
                                           const int* __restrict__ pbb,
                                           int2* __restrict__ tmp) {
    __shared__ int hist[NBUK];
    __shared__ int base[NBUK];
    for (int k = threadIdx.x; k < NBUK; k += 256) hist[k] = 0;
    __syncthreads();
    int b = blockIdx.x;
    int e0 = b * EPB, e1 = min(NE, e0 + EPB);
    for (int i = e0 + threadIdx.x; i < e1; i += 256)
        atomicAdd(&hist[dst[i] >> 6], 1);
    __syncthreads();
    for (int k = threadIdx.x; k < NBUK; k += 256) {
        if (hist[k]) base[k] = bucketBase[k] + pbb[k * NBLK + b];
        hist[k] = 0;                   // reuse as cursor
    }
    __syncthreads();
    for (int i = e0 + threadIdx.x; i < e1; i += 256) {
        int d = dst[i];
        int k = d >> 6;
        int pos = base[k] + atomicAdd(&hist[k], 1);
        tmp[pos] = make_int2(((d & 63) << 16) | src[i], __float_as_int(w[i]));
    }
}

__global__ __launch_bounds__(256) void kB(const int2* __restrict__ tmp,
                                          const int* __restrict__ bucketBase,
                                          int* __restrict__ rowptr,
                                          float* __restrict__ dinv,
                                          float* __restrict__ selfc,
                                          int2* __restrict__ sedge) {
    __shared__ int   cnt[64];
    __shared__ float degs[64];
    __shared__ int   curs[64];
    int b = blockIdx.x;
    int tid = threadIdx.x;
    if (tid < 64) { cnt[tid] = 0; degs[tid] = 0.f; }
    __syncthreads();
    int s0 = bucketBase[b], s1 = bucketBase[b + 1];
    for (int p = s0 + tid; p < s1; p += 256) {
        int2 e = tmp[p];
        int n6 = e.x >> 16;
        atomicAdd(&cnt[n6], 1);
        atomicAdd(&degs[n6], __int_as_float(e.y));
    }
    __syncthreads();
    if (tid < 64) {
        int c = cnt[tid];
        int inc = c;
        for (int off = 1; off < 64; off *= 2) {
            int u = __shfl_up(inc, off);
            if (tid >= off) inc += u;
        }
        int ex = inc - c;
        curs[tid] = ex;
        int node = b * 64 + tid;
        if (node < NN) {
            rowptr[node] = s0 + ex;
            float deg = 1.0f + degs[tid];
            float r = rsqrtf(deg);
            dinv[node] = r;
            selfc[node] = r * r;
        }
    }
    __syncthreads();
    for (int p = s0 + tid; p < s1; p += 256) {
        int2 e = tmp[p];
        int n6 = e.x >> 16;
        int pos = s0 + atomicAdd(&curs[n6], 1);
        sedge[pos] = make_int2(e.x & 0xFFFF, e.y);
    }
}

__global__ void k_coef(const int* __restrict__ rowptr, const float* __restrict__ dinv,
                       int2* __restrict__ sedge) {
    int r = blockIdx.x * blockDim.x + threadIdx.x;
    if (r >= NN) return;
    int e0 = rowptr[r], e1 = rowptr[r + 1];
    float dr = dinv[r];
    for (int p = e0; p < e1; ++p) {
        int2 e = sedge[p];
        float c = dinv[e.x] * __int_as_float(e.y) * dr;
        sedge[p] = make_int2(e.x, __float_as_int(c));
    }
}

// ====== aggregation (gather): out[n] = selfc[n]*h[n] + sum coef*h[src] ======
// 4-deep MLP unroll: 4 independent gathers in flight per lane-group.

template<int F, bool BRELU>
__global__ void k_agg(const float* __restrict__ h, const int* __restrict__ rowptr,
                      const int2* __restrict__ se, const float* __restrict__ selfc,
                      const float* __restrict__ bias, float* __restrict__ out, int n) {
    constexpr int G = F / 4;                     // lanes per node (float4 each)
    constexpr int NPB = 256 / G;
    int gid = blockIdx.x * NPB + threadIdx.x / G;
    int lane = threadIdx.x & (G - 1);
    if (gid >= n) return;
    const float4* h4 = (const float4*)h;
    float sc = selfc[gid];
    float4 a = h4[(long long)gid * G + lane];
    float4 acc0 = make_float4(a.x * sc, a.y * sc, a.z * sc, a.w * sc);
    float4 acc1 = make_float4(0.f, 0.f, 0.f, 0.f);
    float4 acc2 = acc1, acc3 = acc1;
    int e0 = rowptr[gid], e1 = rowptr[gid + 1];
    int p = e0;
    for (; p + 4 <= e1; p += 4) {
        int2 d0 = se[p], d1 = se[p + 1], d2 = se[p + 2], d3 = se[p + 3];
        float4 v0 = h4[(long long)d0.x * G + lane];
        float4 v1 = h4[(long long)d1.x * G + lane];
        float4 v2 = h4[(long long)d2.x * G + lane];
        float4 v3 = h4[(long long)d3.x * G + lane];
        float c0 = __int_as_float(d0.y), c1 = __int_as_float(d1.y);
        float c2 = __int_as_float(d2.y), c3 = __int_as_float(d3.y);
        acc0.x += c0 * v0.x; acc0.y += c0 * v0.y; acc0.z += c0 * v0.z; acc0.w += c0 * v0.w;
        acc1.x += c1 * v1.x; acc1.y += c1 * v1.y; acc1.z += c1 * v1.z; acc1.w += c1 * v1.w;
        acc2.x += c2 * v2.x; acc2.y += c2 * v2.y; acc2.z += c2 * v2.z; acc2.w += c2 * v2.w;
        acc3.x += c3 * v3.x; acc3.y += c3 * v3.y; acc3.z += c3 * v3.z; acc3.w += c3 * v3.w;
    }
    for (; p < e1; ++p) {
        int2 ed = se[p];
        float c = __int_as_float(ed.y);
        float4 hv = h4[(long long)ed.x * G + lane];
        acc0.x += c * hv.x; acc0.y += c * hv.y; acc0.z += c * hv.z; acc0.w += c * hv.w;
    }
    float4 acc;
    acc.x = (acc0.x + acc1.x) + (acc2.x + acc3.x);
    acc.y = (acc0.y + acc1.y) + (acc2.y + acc3.y);
    acc.z = (acc0.z + acc1.z) + (acc2.z + acc3.z);
    acc.w = (acc0.w + acc1.w) + (acc2.w + acc3.w);
    if (BRELU) {
        float4 bv = ((const float4*)bias)[lane];
        acc.x = fmaxf(acc.x + bv.x, 0.0f); acc.y = fmaxf(acc.y + bv.y, 0.0f);
        acc.z = fmaxf(acc.z + bv.z, 0.0f); acc.w = fmaxf(acc.w + bv.w, 0.0f);
    }
    ((float4*)out)[(long long)gid * G + lane] = acc;
}

// ================= dense layer: out = [relu](h @ W + b) =================

template<int FIN, int FOUT, bool RELU, bool BIAS>
__global__ __launch_bounds__(256) void k_gemm(const float* __restrict__ h,
                                              const float* __restrict__ W,
                                              const float* __restrict__ b,
                                              float* __restrict__ out, int n) {
    constexpr int TC = FOUT / 4;
    constexpr int TR = 256 / TC;
    constexpr int R  = 64 / TR;
    constexpr int SA = 68;
    constexpr int CB = FIN / 4;

    __shared__ float  hT[FIN * SA];
    __shared__ float4 Wl[FIN * TC];
    __shared__ float4 bl[TC];

    int tid = threadIdx.x;
    int rowbase = blockIdx.x * 64;

    for (int i = tid; i < FIN * TC; i += 256) Wl[i] = ((const float4*)W)[i];
    if (BIAS && tid < TC) bl[tid] = ((const float4*)b)[tid];

    for (int blk = tid; blk < 16 * CB; blk += 256) {
        int br = blk / CB, bc = blk % CB;
        float4 v[4];
        #pragma unroll
        for (int i = 0; i < 4; ++i) {
            int rr = rowbase + 4 * br + i;
            if (rr >= n) rr = n - 1;
            v[i] = *(const float4*)(h + (long long)rr * FIN + 4 * bc);
        }
        #pragma unroll
        for (int j = 0; j < 4; ++j) {
            float4 t;
            t.x = ((float*)&v[0])[j];
            t.y = ((float*)&v[1])[j];
            t.z = ((float*)&v[2])[j];
            t.w = ((float*)&v[3])[j];
            *(float4*)&hT[(4 * bc + j) * SA + 4 * br] = t;
        }
    }
    __syncthreads();

    int tc = tid % TC;
    int r0 = (tid / TC) * R;

    float4 acc[R];
    float4 binit = BIAS ? bl[tc] : make_float4(0.f, 0.f, 0.f, 0.f);
    #pragma unroll
    for (int r = 0; r < R; ++r) acc[r] = binit;

    #pragma unroll 4
    for (int fi = 0; fi < FIN; ++fi) {
        float4 wv = Wl[fi * TC + tc];
        float a[R];
        if constexpr (R >= 4) {
            #pragma unroll
            for (int rb = 0; rb < R / 4; ++rb) {
                float4 t = *(const float4*)&hT[fi * SA + r0 + 4 * rb];
                a[4 * rb + 0] = t.x; a[4 * rb + 1] = t.y;
                a[4 * rb + 2] = t.z; a[4 * rb + 3] = t.w;
            }
        } else if constexpr (R == 2) {
            float2 t = *(const float2*)&hT[fi * SA + r0];
            a[0] = t.x; a[1] = t.y;
        } else {
            a[0] = hT[fi * SA + r0];
        }
        #pragma unroll
        for (int r = 0; r < R; ++r) {
            acc[r].x += a[r] * wv.x; acc[r].y += a[r] * wv.y;
            acc[r].z += a[r] * wv.z; acc[r].w += a[r] * wv.w;
        }
    }

    #pragma unroll
    for (int r = 0; r < R; ++r) {
        int row = rowbase + r0 + r;
        if (row < n) {
            float4 v = acc[r];
            if (RELU) {
                v.x = fmaxf(v.x, 0.f); v.y = fmaxf(v.y, 0.f);
                v.z = fmaxf(v.z, 0.f); v.w = fmaxf(v.w, 0.f);
            }
            *(float4*)(out + (long long)row * FOUT + 4 * tc) = v;
        }
    }
}

// ================= global add pool + relu (two-phase, batch sorted) =================

__global__ __launch_bounds__(128) void k_pool1(const float* __restrict__ h,
                                               const int* __restrict__ batch,
                                               float* __restrict__ part, int n) {
    int g = blockIdx.x / PSLICE;
    int s = blockIdx.x % PSLICE;
    int lo = 0, hi = n;
    while (lo < hi) { int m = (lo + hi) >> 1; if (batch[m] < g) lo = m + 1; else hi = m; }
    int start = lo;
    hi = n;
    while (lo < hi) { int m = (lo + hi) >> 1; if (batch[m] < g + 1) lo = m + 1; else hi = m; }
    int end = lo;
    int len = end - start;
    int a = start + (int)((long long)len * s / PSLICE);
    int bnd = start + (int)((long long)len * (s + 1) / PSLICE);
    int f = threadIdx.x;
    float a0 = 0.f, a1 = 0.f, a2 = 0.f, a3 = 0.f;
    int i = a;
    for (; i + 4 <= bnd; i += 4) {
        a0 += h[(long long)(i + 0) * 128 + f];
        a1 += h[(long long)(i + 1) * 128 + f];
        a2 += h[(long long)(i + 2) * 128 + f];
        a3 += h[(long long)(i + 3) * 128 + f];
    }
    for (; i < bnd; ++i) a0 += h[(long long)i * 128 + f];
    part[(long long)blockIdx.x * 128 + f] = (a0 + a1) + (a2 + a3);
}

__global__ __launch_bounds__(128) void k_pool2(const float* __restrict__ part,
                                               float* __restrict__ out) {
    int g = blockIdx.x;
    int f = threadIdx.x;
    float acc = 0.f;
    #pragma unroll
    for (int s = 0; s < PSLICE; ++s)
        acc += part[(long long)(g * PSLICE + s) * 128 + f];
    out[g * 128 + f] = fmaxf(acc, 0.0f);
}

// ================= launch =================

static inline int cdiv(long long a, int b) { return (int)((a + b - 1) / b); }

extern "C" void kernel_launch(void* const* d_in, const int* in_sizes, int n_in,
                              void* d_out, int out_size, void* d_ws, size_t ws_size,
                              hipStream_t stream) {
    const float* x    = (const float*)d_in[0];
    const int*   src  = (const int*)d_in[1];
    const int*   dst  = src + NE;
    const float* ew   = (const float*)d_in[2];
    const int*   batch= (const int*)d_in[3];
    const float* W1 = (const float*)d_in[4];  const float* b1 = (const float*)d_in[5];
    const float* W2 = (const float*)d_in[6];  const float* b2 = (const float*)d_in[7];
    const float* W3 = (const float*)d_in[8];  const float* b3 = (const float*)d_in[9];
    const float* W4 = (const float*)d_in[10]; const float* b4 = (const float*)d_in[11];
    const float* W5 = (const float*)d_in[12]; const float* b5 = (const float*)d_in[13];
    float* out = (float*)d_out;

    // ---- workspace layout (floats) ----
    float* ws = (float*)d_ws;
    int*   rowptr = (int*)ws;                          // [50004] ints
    int2*  sedge  = (int2*)(ws + 50004);               // [NE] int2
    float* selfc  = ws + 50004 + 2 * (size_t)NE;       // [NN]
    float* dinv   = selfc + NN;                        // [NN]
    float* bufA   = dinv + NN;                         // [NN*64]
    float* bufB   = bufA + (size_t)NN * 64;            // [NN*128]
    // CSR-build scratch overlays dead regions:
    int*  pbb        = (int*)bufA;                     // NBUK*NBLK
    int*  bucketCnt  = pbb + NBUK * NBLK;              // NBUK+1
    int*  bucketBase = bucketCnt + NBUK + 1;           // NBUK+1
    int2* tmp        = (int2*)bufB;                    // NE
    float* part      = bufA;                           // NG*PSLICE*128 (pool partials)

    const int T = 256;

    // ---- CSR build (shared across all 5 layers) ----
    k_bzero<<<cdiv(NBUK + 1, T), T, 0, stream>>>(bucketCnt);
    kA1<<<NBLK, T, 0, stream>>>(dst, bucketCnt, pbb);
    k_bscan<<<1, 1024, 0, stream>>>(bucketCnt, bucketBase, rowptr);
    kA2<<<NBLK, T, 0, stream>>>(src, dst, ew, bucketBase, pbb, tmp);
    kB<<<NBUK, T, 0, stream>>>(tmp, bucketBase, rowptr, dinv, selfc, sedge);
    k_coef<<<cdiv(NN, T), T, 0, stream>>>(rowptr, dinv, sedge);

    // ---- layer 1: 64 -> 16 (transform first since Fout < Fin) ----
    k_gemm<64, 16, false, false><<<cdiv(NN, 64), T, 0, stream>>>(x, W1, nullptr, bufA, NN);
    k_agg<16, true><<<cdiv(NN, 64), T, 0, stream>>>(bufA, rowptr, sedge, selfc, b1, bufB, NN);

    // ---- layer 2: 16 -> 32 (aggregate first) ----
    k_agg<16, false><<<cdiv(NN, 64), T, 0, stream>>>(bufB, rowptr, sedge, selfc, nullptr, bufA, NN);
    k_gemm<16, 32, true, true><<<cdiv(NN, 64), T, 0, stream>>>(bufA, W2, b2, bufB, NN);

    // ---- layer 3: 32 -> 64 ----
    k_agg<32, false><<<cdiv(NN, 32), T, 0, stream>>>(bufB, rowptr, sedge, selfc, nullptr, bufA, NN);
    k_gemm<32, 64, true, true><<<cdiv(NN, 64), T, 0, stream>>>(bufA, W3, b3, bufB, NN);

    // ---- layer 4: 64 -> 64 ----
    k_agg<64, false><<<cdiv(NN, 16), T, 0, stream>>>(bufB, rowptr, sedge, selfc, nullptr, bufA, NN);
    k_gemm<64, 64, true, true><<<cdiv(NN, 64), T, 0, stream>>>(bufA, W4, b4, bufB, NN);

    // ---- layer 5: 64 -> 128 ----
    k_agg<64, false><<<cdiv(NN, 16), T, 0, stream>>>(bufB, rowptr, sedge, selfc, nullptr, bufA, NN);
    k_gemm<64, 128, false, true><<<cdiv(NN, 64), T, 0, stream>>>(bufA, W5, b5, bufB, NN);

    // ---- global add pool + relu (two-phase) ----
    k_pool1<<<NG * PSLICE, 128, 0, stream>>>(bufB, batch, part, NN);
    k_pool2<<<NG, 128, 0, stream>>>(part, out);
}

// Round 6
// 247.160 us; speedup vs baseline: 3.3662x; 1.0624x over previous
//
#include <hip/hip_runtime.h>

#define NN 50000
#define NE 800000
#define NG 256
#define NBUK 782            // ceil(NN/64)
#define EPB 4096            // edges per block in bucket passes
#define NBLK 196            // ceil(NE/EPB)
#define PSLICE 8            // pool slices per graph

// ================= CSR build via two-level counting sort =================

__global__ void k_bzero(int* bucketCnt) {
    int i = blockIdx.x * blockDim.x + threadIdx.x;
    if (i <= NBUK) bucketCnt[i] = 0;
}

__global__ __launch_bounds__(256) void kA1(const int* __restrict__ dst,
                                           int* __restrict__ bucketCnt,
                                           int* __restrict__ pbb) {
    __shared__ int hist[NBUK];
    for (int k = threadIdx.x; k < NBUK; k += 256) hist[k] = 0;
    __syncthreads();
    int b = blockIdx.x;
    int e0 = b * EPB, e1 = min(NE, e0 + EPB);
    for (int i = e0 + threadIdx.x; i < e1; i += 256)
        atomicAdd(&hist[dst[i] >> 6], 1);
    __syncthreads();
    for (int k = threadIdx.x; k < NBUK; k += 256) {
        int c = hist[k];
        if (c) pbb[k * NBLK + b] = atomicAdd(&bucketCnt[k], c);
    }
}

__global__ __launch_bounds__(1024) void k_bscan(const int* __restrict__ bucketCnt,
                                                int* __restrict__ bucketBase,
                                                int* __restrict__ rowptr) {
    __shared__ int wsum[16];
    int tid = threadIdx.x;
    int v = (tid < NBUK) ? bucketCnt[tid] : 0;
    int inc = v;
    for (int off = 1; off < 64; off *= 2) {
        int u = __shfl_up(inc, off);
        if ((tid & 63) >= off) inc += u;
    }
    if ((tid & 63) == 63) wsum[tid >> 6] = inc;
    __syncthreads();
    if (tid < 16) {
        int w = wsum[tid], winc = w;
        for (int off = 1; off < 16; off *= 2) {
            int u = __shfl_up(winc, off);
            if (tid >= off) winc += u;
        }
        wsum[tid] = winc - w;
    }
    __syncthreads();
    int ex = inc - v + wsum[tid >> 6];
    if (tid <= NBUK) bucketBase[tid] = ex;
    if (tid == 0) rowptr[NN] = NE;
}

__global__ __launch_bounds__(256) void kA2(const int* __restrict__ src,
                                           const int* __restrict__ dst,
                                           const float* __restrict__ w,
                                           const int* __restrict__ bucketBase,
                                           const int* __restrict__ pbb,
                                           int2* __restrict__ tmp) {
    __shared__ int hist[NBUK];
    __shared__ int base[NBUK];
    for (int k = threadIdx.x; k < NBUK; k += 256) hist[k] = 0;
    __syncthreads();
    int b = blockIdx.x;
    int e0 = b * EPB, e1 = min(NE, e0 + EPB);
    for (int i = e0 + threadIdx.x; i < e1; i += 256)
        atomicAdd(&hist[dst[i] >> 6], 1);
    __syncthreads();
    for (int k = threadIdx.x; k < NBUK; k += 256) {
        if (hist[k]) base[k] = bucketBase[k] + pbb[k * NBLK + b];
        hist[k] = 0;                   // reuse as cursor
    }
    __syncthreads();
    for (int i = e0 + threadIdx.x; i < e1; i += 256) {
        int d = dst[i];
        int k = d >> 6;
        int pos = base[k] + atomicAdd(&hist[k], 1);
        tmp[pos] = make_int2(((d & 63) << 16) | src[i], __float_as_int(w[i]));
    }
}

__global__ __launch_bounds__(256) void kB(const int2* __restrict__ tmp,
                                          const int* __restrict__ bucketBase,
                                          int* __restrict__ rowptr,
                                          float* __restrict__ dinv,
                                          float* __restrict__ selfc,
                                          int2* __restrict__ sedge) {
    __shared__ int   cnt[64];
    __shared__ float degs[64];
    __shared__ int   curs[64];
    int b = blockIdx.x;
    int tid = threadIdx.x;
    if (tid < 64) { cnt[tid] = 0; degs[tid] = 0.f; }
    __syncthreads();
    int s0 = bucketBase[b], s1 = bucketBase[b + 1];
    for (int p = s0 + tid; p < s1; p += 256) {
        int2 e = tmp[p];
        int n6 = e.x >> 16;
        atomicAdd(&cnt[n6], 1);
        atomicAdd(&degs[n6], __int_as_float(e.y));
    }
    __syncthreads();
    if (tid < 64) {
        int c = cnt[tid];
        int inc = c;
        for (int off = 1; off < 64; off *= 2) {
            int u = __shfl_up(inc, off);
            if (tid >= off) inc += u;
        }
        int ex = inc - c;
        curs[tid] = ex;
        int node = b * 64 + tid;
        if (node < NN) {
            rowptr[node] = s0 + ex;
            float deg = 1.0f + degs[tid];
            float r = rsqrtf(deg);
            dinv[node] = r;
            selfc[node] = r * r;
        }
    }
    __syncthreads();
    for (int p = s0 + tid; p < s1; p += 256) {
        int2 e = tmp[p];
        int n6 = e.x >> 16;
        int pos = s0 + atomicAdd(&curs[n6], 1);
        sedge[pos] = make_int2(e.x & 0xFFFF, e.y);
    }
}

__global__ void k_coef(const int* __restrict__ rowptr, const float* __restrict__ dinv,
                       int2* __restrict__ sedge) {
    int r = blockIdx.x * blockDim.x + threadIdx.x;
    if (r >= NN) return;
    int e0 = rowptr[r], e1 = rowptr[r + 1];
    float dr = dinv[r];
    for (int p = e0; p < e1; ++p) {
        int2 e = sedge[p];
        float c = dinv[e.x] * __int_as_float(e.y) * dr;
        sedge[p] = make_int2(e.x, __float_as_int(c));
    }
}

// ====== edge-loop body: 8-deep / 4-deep / scalar accumulate (macro-free) ======

template<int G>
__device__ __forceinline__ float4 agg_row(const float4* __restrict__ h4,
                                          const int2* __restrict__ se,
                                          int lane, int e0, int e1, float4 acc_init) {
    float4 acc[8];
    acc[0] = acc_init;
    #pragma unroll
    for (int j = 1; j < 8; ++j) acc[j] = make_float4(0.f, 0.f, 0.f, 0.f);
    int p = e0;
    for (; p + 8 <= e1; p += 8) {
        int2 d[8]; float4 v[8];
        #pragma unroll
        for (int j = 0; j < 8; ++j) d[j] = se[p + j];
        #pragma unroll
        for (int j = 0; j < 8; ++j) v[j] = h4[(long long)d[j].x * G + lane];
        #pragma unroll
        for (int j = 0; j < 8; ++j) {
            float c = __int_as_float(d[j].y);
            acc[j].x += c * v[j].x; acc[j].y += c * v[j].y;
            acc[j].z += c * v[j].z; acc[j].w += c * v[j].w;
        }
    }
    for (; p + 4 <= e1; p += 4) {
        int2 d[4]; float4 v[4];
        #pragma unroll
        for (int j = 0; j < 4; ++j) d[j] = se[p + j];
        #pragma unroll
        for (int j = 0; j < 4; ++j) v[j] = h4[(long long)d[j].x * G + lane];
        #pragma unroll
        for (int j = 0; j < 4; ++j) {
            float c = __int_as_float(d[j].y);
            acc[j].x += c * v[j].x; acc[j].y += c * v[j].y;
            acc[j].z += c * v[j].z; acc[j].w += c * v[j].w;
        }
    }
    for (; p < e1; ++p) {
        int2 ed = se[p];
        float c = __int_as_float(ed.y);
        float4 hv = h4[(long long)ed.x * G + lane];
        acc[0].x += c * hv.x; acc[0].y += c * hv.y;
        acc[0].z += c * hv.z; acc[0].w += c * hv.w;
    }
    #pragma unroll
    for (int j = 4; j < 8; ++j) {
        acc[j - 4].x += acc[j].x; acc[j - 4].y += acc[j].y;
        acc[j - 4].z += acc[j].z; acc[j - 4].w += acc[j].w;
    }
    float4 r;
    r.x = (acc[0].x + acc[1].x) + (acc[2].x + acc[3].x);
    r.y = (acc[0].y + acc[1].y) + (acc[2].y + acc[3].y);
    r.z = (acc[0].z + acc[1].z) + (acc[2].z + acc[3].z);
    r.w = (acc[0].w + acc[1].w) + (acc[2].w + acc[3].w);
    return r;
}

// ====== standalone aggregation (layer 1): out = agg(h) [+bias,relu] ======

template<int F, bool BRELU>
__global__ void k_agg(const float* __restrict__ h, const int* __restrict__ rowptr,
                      const int2* __restrict__ se, const float* __restrict__ selfc,
                      const float* __restrict__ bias, float* __restrict__ out, int n) {
    constexpr int G = F / 4;
    constexpr int NPB = 256 / G;
    int gid = blockIdx.x * NPB + threadIdx.x / G;
    int lane = threadIdx.x & (G - 1);
    if (gid >= n) return;
    const float4* h4 = (const float4*)h;
    float sc = selfc[gid];
    float4 a = h4[(long long)gid * G + lane];
    float4 ai = make_float4(a.x * sc, a.y * sc, a.z * sc, a.w * sc);
    float4 acc = agg_row<G>(h4, se, lane, rowptr[gid], rowptr[gid + 1], ai);
    if (BRELU) {
        float4 bv = ((const float4*)bias)[lane];
        acc.x = fmaxf(acc.x + bv.x, 0.0f); acc.y = fmaxf(acc.y + bv.y, 0.0f);
        acc.z = fmaxf(acc.z + bv.z, 0.0f); acc.w = fmaxf(acc.w + bv.w, 0.0f);
    }
    ((float4*)out)[(long long)gid * G + lane] = acc;
}

// ====== fused aggregate + dense: out = [relu](agg(h) @ W + b) ======
// Block handles 64 output rows. Phase 1: aggregate into LDS (transposed).
// Phase 2: register-tiled GEMM from LDS.

template<int FAGG, int FOUT, bool RELU>
__global__ __launch_bounds__(256) void k_aggemm(const float* __restrict__ h,
                                                const int* __restrict__ rowptr,
                                                const int2* __restrict__ se,
                                                const float* __restrict__ selfc,
                                                const float* __restrict__ W,
                                                const float* __restrict__ b,
                                                float* __restrict__ out, int n) {
    constexpr int G    = FAGG / 4;    // lanes per node in agg phase
    constexpr int NPP  = 256 / G;     // nodes per agg pass
    constexpr int PASS = 64 / NPP;
    constexpr int SA   = 68;          // LDS row stride
    constexpr int TC   = FOUT / 4;    // thread-cols in gemm phase
    constexpr int TR   = 256 / TC;
    constexpr int R    = 64 / TR;     // rows per thread

    __shared__ float  hT[FAGG * SA];
    __shared__ float4 Wl[FAGG * TC];
    __shared__ float4 bl[TC];

    int tid = threadIdx.x;
    int rowbase = blockIdx.x * 64;

    for (int i = tid; i < FAGG * TC; i += 256) Wl[i] = ((const float4*)W)[i];
    if (tid < TC) bl[tid] = ((const float4*)b)[tid];

    // ---- phase 1: aggregate 64 rows into hT (transposed) ----
    const float4* h4 = (const float4*)h;
    int lane = tid & (G - 1);
    int sub  = tid / G;
    #pragma unroll
    for (int ps = 0; ps < PASS; ++ps) {
        int lrow = ps * NPP + sub;
        int gid = rowbase + lrow;
        int gidc = (gid < n) ? gid : (n - 1);
        float sc = selfc[gidc];
        float4 a = h4[(long long)gidc * G + lane];
        float4 ai = make_float4(a.x * sc, a.y * sc, a.z * sc, a.w * sc);
        float4 acc = agg_row<G>(h4, se, lane, rowptr[gidc], rowptr[gidc + 1], ai);
        hT[(4 * lane + 0) * SA + lrow] = acc.x;
        hT[(4 * lane + 1) * SA + lrow] = acc.y;
        hT[(4 * lane + 2) * SA + lrow] = acc.z;
        hT[(4 * lane + 3) * SA + lrow] = acc.w;
    }
    __syncthreads();

    // ---- phase 2: gemm ----
    int tc = tid % TC;
    int r0 = (tid / TC) * R;

    float4 acc[R];
    float4 binit = bl[tc];
    #pragma unroll
    for (int r = 0; r < R; ++r) acc[r] = binit;

    #pragma unroll 4
    for (int fi = 0; fi < FAGG; ++fi) {
        float4 wv = Wl[fi * TC + tc];
        float a[R];
        if constexpr (R >= 4) {
            #pragma unroll
            for (int rb = 0; rb < R / 4; ++rb) {
                float4 t = *(const float4*)&hT[fi * SA + r0 + 4 * rb];
                a[4 * rb + 0] = t.x; a[4 * rb + 1] = t.y;
                a[4 * rb + 2] = t.z; a[4 * rb + 3] = t.w;
            }
        } else {
            float2 t = *(const float2*)&hT[fi * SA + r0];
            a[0] = t.x; a[1] = t.y;
        }
        #pragma unroll
        for (int r = 0; r < R; ++r) {
            acc[r].x += a[r] * wv.x; acc[r].y += a[r] * wv.y;
            acc[r].z += a[r] * wv.z; acc[r].w += a[r] * wv.w;
        }
    }

    #pragma unroll
    for (int r = 0; r < R; ++r) {
        int row = rowbase + r0 + r;
        if (row < n) {
            float4 v = acc[r];
            if (RELU) {
                v.x = fmaxf(v.x, 0.f); v.y = fmaxf(v.y, 0.f);
                v.z = fmaxf(v.z, 0.f); v.w = fmaxf(v.w, 0.f);
            }
            *(float4*)(out + (long long)row * FOUT + 4 * tc) = v;
        }
    }
}

// ================= dense layer (layer 1 only) =================

template<int FIN, int FOUT, bool RELU, bool BIAS>
__global__ __launch_bounds__(256) void k_gemm(const float* __restrict__ h,
                                              const float* __restrict__ W,
                                              const float* __restrict__ b,
                                              float* __restrict__ out, int n) {
    constexpr int TC = FOUT / 4;
    constexpr int TR = 256 / TC;
    constexpr int R  = 64 / TR;
    constexpr int SA = 68;
    constexpr int CB = FIN / 4;

    __shared__ float  hT[FIN * SA];
    __shared__ float4 Wl[FIN * TC];
    __shared__ float4 bl[TC];

    int tid = threadIdx.x;
    int rowbase = blockIdx.x * 64;

    for (int i = tid; i < FIN * TC; i += 256) Wl[i] = ((const float4*)W)[i];
    if (BIAS && tid < TC) bl[tid] = ((const float4*)b)[tid];

    for (int blk = tid; blk < 16 * CB; blk += 256) {
        int br = blk / CB, bc = blk % CB;
        float4 v[4];
        #pragma unroll
        for (int i = 0; i < 4; ++i) {
            int rr = rowbase + 4 * br + i;
            if (rr >= n) rr = n - 1;
            v[i] = *(const float4*)(h + (long long)rr * FIN + 4 * bc);
        }
        #pragma unroll
        for (int j = 0; j < 4; ++j) {
            float4 t;
            t.x = ((float*)&v[0])[j];
            t.y = ((float*)&v[1])[j];
            t.z = ((float*)&v[2])[j];
            t.w = ((float*)&v[3])[j];
            *(float4*)&hT[(4 * bc + j) * SA + 4 * br] = t;
        }
    }
    __syncthreads();

    int tc = tid % TC;
    int r0 = (tid / TC) * R;

    float4 acc[R];
    float4 binit = BIAS ? bl[tc] : make_float4(0.f, 0.f, 0.f, 0.f);
    #pragma unroll
    for (int r = 0; r < R; ++r) acc[r] = binit;

    #pragma unroll 4
    for (int fi = 0; fi < FIN; ++fi) {
        float4 wv = Wl[fi * TC + tc];
        float a[R];
        if constexpr (R >= 4) {
            #pragma unroll
            for (int rb = 0; rb < R / 4; ++rb) {
                float4 t = *(const float4*)&hT[fi * SA + r0 + 4 * rb];
                a[4 * rb + 0] = t.x; a[4 * rb + 1] = t.y;
                a[4 * rb + 2] = t.z; a[4 * rb + 3] = t.w;
            }
        } else if constexpr (R == 2) {
            float2 t = *(const float2*)&hT[fi * SA + r0];
            a[0] = t.x; a[1] = t.y;
        } else {
            a[0] = hT[fi * SA + r0];
        }
        #pragma unroll
        for (int r = 0; r < R; ++r) {
            acc[r].x += a[r] * wv.x; acc[r].y += a[r] * wv.y;
            acc[r].z += a[r] * wv.z; acc[r].w += a[r] * wv.w;
        }
    }

    #pragma unroll
    for (int r = 0; r < R; ++r) {
        int row = rowbase + r0 + r;
        if (row < n) {
            float4 v = acc[r];
            if (RELU) {
                v.x = fmaxf(v.x, 0.f); v.y = fmaxf(v.y, 0.f);
                v.z = fmaxf(v.z, 0.f); v.w = fmaxf(v.w, 0.f);
            }
            *(float4*)(out + (long long)row * FOUT + 4 * tc) = v;
        }
    }
}

// ================= global add pool + relu (two-phase, batch sorted) =================

__global__ __launch_bounds__(128) void k_pool1(const float* __restrict__ h,
                                               const int* __restrict__ batch,
                                               float* __restrict__ part, int n) {
    int g = blockIdx.x / PSLICE;
    int s = blockIdx.x % PSLICE;
    int lo = 0, hi = n;
    while (lo < hi) { int m = (lo + hi) >> 1; if (batch[m] < g) lo = m + 1; else hi = m; }
    int start = lo;
    hi = n;
    while (lo < hi) { int m = (lo + hi) >> 1; if (batch[m] < g + 1) lo = m + 1; else hi = m; }
    int end = lo;
    int len = end - start;
    int a = start + (int)((long long)len * s / PSLICE);
    int bnd = start + (int)((long long)len * (s + 1) / PSLICE);
    int f = threadIdx.x;
    float a0 = 0.f, a1 = 0.f, a2 = 0.f, a3 = 0.f;
    int i = a;
    for (; i + 4 <= bnd; i += 4) {
        a0 += h[(long long)(i + 0) * 128 + f];
        a1 += h[(long long)(i + 1) * 128 + f];
        a2 += h[(long long)(i + 2) * 128 + f];
        a3 += h[(long long)(i + 3) * 128 + f];
    }
    for (; i < bnd; ++i) a0 += h[(long long)i * 128 + f];
    part[(long long)blockIdx.x * 128 + f] = (a0 + a1) + (a2 + a3);
}

__global__ __launch_bounds__(128) void k_pool2(const float* __restrict__ part,
                                               float* __restrict__ out) {
    int g = blockIdx.x;
    int f = threadIdx.x;
    float acc = 0.f;
    #pragma unroll
    for (int s = 0; s < PSLICE; ++s)
        acc += part[(long long)(g * PSLICE + s) * 128 + f];
    out[g * 128 + f] = fmaxf(acc, 0.0f);
}

// ================= launch =================

static inline int cdiv(long long a, int b) { return (int)((a + b - 1) / b); }

extern "C" void kernel_launch(void* const* d_in, const int* in_sizes, int n_in,
                              void* d_out, int out_size, void* d_ws, size_t ws_size,
                              hipStream_t stream) {
    const float* x    = (const float*)d_in[0];
    const int*   src  = (const int*)d_in[1];
    const int*   dst  = src + NE;
    const float* ew   = (const float*)d_in[2];
    const int*   batch= (const int*)d_in[3];
    const float* W1 = (const float*)d_in[4];  const float* b1 = (const float*)d_in[5];
    const float* W2 = (const float*)d_in[6];  const float* b2 = (const float*)d_in[7];
    const float* W3 = (const float*)d_in[8];  const float* b3 = (const float*)d_in[9];
    const float* W4 = (const float*)d_in[10]; const float* b4 = (const float*)d_in[11];
    const float* W5 = (const float*)d_in[12]; const float* b5 = (const float*)d_in[13];
    float* out = (float*)d_out;

    // ---- workspace layout (floats) ----
    float* ws = (float*)d_ws;
    int*   rowptr = (int*)ws;                          // [50004] ints
    int2*  sedge  = (int2*)(ws + 50004);               // [NE] int2
    float* selfc  = ws + 50004 + 2 * (size_t)NE;       // [NN]
    float* dinv   = selfc + NN;                        // [NN]
    float* bufA   = dinv + NN;                         // [NN*64]
    float* bufB   = bufA + (size_t)NN * 64;            // [NN*128]
    // CSR-build scratch overlays dead regions:
    int*  pbb        = (int*)bufA;                     // NBUK*NBLK
    int*  bucketCnt  = pbb + NBUK * NBLK;              // NBUK+1
    int*  bucketBase = bucketCnt + NBUK + 1;           // NBUK+1
    int2* tmp        = (int2*)bufB;                    // NE
    float* part      = bufA;                           // NG*PSLICE*128 (pool partials)

    const int T = 256;
    const int GB = cdiv(NN, 64);   // 782 row-blocks

    // ---- CSR build (shared across all 5 layers) ----
    k_bzero<<<cdiv(NBUK + 1, T), T, 0, stream>>>(bucketCnt);
    kA1<<<NBLK, T, 0, stream>>>(dst, bucketCnt, pbb);
    k_bscan<<<1, 1024, 0, stream>>>(bucketCnt, bucketBase, rowptr);
    kA2<<<NBLK, T, 0, stream>>>(src, dst, ew, bucketBase, pbb, tmp);
    kB<<<NBUK, T, 0, stream>>>(tmp, bucketBase, rowptr, dinv, selfc, sedge);
    k_coef<<<cdiv(NN, T), T, 0, stream>>>(rowptr, dinv, sedge);

    // ---- layer 1: 64 -> 16 (transform first, then agg+bias+relu) ----
    k_gemm<64, 16, false, false><<<GB, T, 0, stream>>>(x, W1, nullptr, bufA, NN);
    k_agg<16, true><<<cdiv(NN, 64), T, 0, stream>>>(bufA, rowptr, sedge, selfc, b1, bufB, NN);

    // ---- layers 2-5: fused aggregate + dense ----
    k_aggemm<16, 32,  true ><<<GB, T, 0, stream>>>(bufB, rowptr, sedge, selfc, W2, b2, bufA, NN);
    k_aggemm<32, 64,  true ><<<GB, T, 0, stream>>>(bufA, rowptr, sedge, selfc, W3, b3, bufB, NN);
    k_aggemm<64, 64,  true ><<<GB, T, 0, stream>>>(bufB, rowptr, sedge, selfc, W4, b4, bufA, NN);
    k_aggemm<64, 128, false><<<GB, T, 0, stream>>>(bufA, rowptr, sedge, selfc, W5, b5, bufB, NN);

    // ---- global add pool + relu (two-phase) ----
    k_pool1<<<NG * PSLICE, 128, 0, stream>>>(bufB, batch, part, NN);
    k_pool2<<<NG, 128, 0, stream>>>(part, out);
}